// Round 4
// baseline (277.684 us; speedup 1.0000x reference)
//
#include <hip/hip_runtime.h>
#include <hip/hip_bf16.h>

typedef __attribute__((ext_vector_type(8))) short short8;   // 8 bf16 = 4 VGPRs (MFMA A/B frag)
typedef __attribute__((ext_vector_type(4))) short short4v;  // 4 bf16 = 8 B
typedef __attribute__((ext_vector_type(4))) float floatx4;  // MFMA C/D frag

#define MFMA(a, b, c) __builtin_amdgcn_mfma_f32_16x16x32_bf16((a), (b), (c), 0, 0, 0)

// fp32 -> bf16, round-to-nearest-even (bit trick; inputs are finite)
__device__ __forceinline__ short f2bf(float f) {
    unsigned u = __float_as_uint(f);
    u += 0x7fffu + ((u >> 16) & 1u);
    return (short)(u >> 16);
}

__device__ __forceinline__ short8 pack_bf16(floatx4 a, floatx4 b) {
    short8 r;
    r[0] = f2bf(a.x); r[1] = f2bf(a.y); r[2] = f2bf(a.z); r[3] = f2bf(a.w);
    r[4] = f2bf(b.x); r[5] = f2bf(b.y); r[6] = f2bf(b.z); r[7] = f2bf(b.w);
    return r;
}

// ---------------------------------------------------------------------------
// Cayley via Neumann/Horner series on one block (256 threads, 4 waves).
//   B = skew(X)/2 (||B||_2 ~ 0.16);  C = I + 2*(B + B^2 + ...)
// NSTEP=6 -> truncation ~4e-5, far below bf16 rounding.
// mode 0: write C row-major bf16 (B-operand array)
// mode 1: write C^T * diag bf16  (A-operand array, diag folded)
// ---------------------------------------------------------------------------
__device__ void cayley64(const float* __restrict__ X, const float* __restrict__ dg,
                         short* outArr, int mode,
                         short* Brow, float* Bcol, short* T0, short* T1, int tid)
{
    int i0 = (tid * 16) >> 6;
    int j0 = (tid * 16) & 63;
#pragma unroll
    for (int s = 0; s < 16; ++s) {
        int i = i0, j = j0 + s;
        float b = 0.f;
        if (i > j)      b =  0.5f * X[i * 64 + j];
        else if (i < j) b = -0.5f * X[j * 64 + i];
        Brow[i * 72 + j] = f2bf(b);
        Bcol[j * 68 + i] = b;
        T0[j * 72 + i]   = f2bf(b);
    }
    __syncthreads();

    int lane = tid & 63, w = tid >> 6, m = lane & 15, q = lane >> 4;
    int arow = (w * 16 + m) * 72;
    short8 a0 = *(const short8*)&Brow[arow + q * 8];
    short8 a1 = *(const short8*)&Brow[arow + 32 + q * 8];

    short* Tbuf[2] = {T0, T1};
    int cur = 0;
    const int NSTEP = 6;
    for (int step = 0; step < NSTEP; ++step) {
        bool last = (step == NSTEP - 1);
        short* Tr = Tbuf[cur];
        short* Tw = Tbuf[cur ^ 1];
#pragma unroll
        for (int c = 0; c < 4; ++c) {
            int coff = c * 16 + m;
            short8 b0 = *(const short8*)&Tr[coff * 72 + q * 8];
            short8 b1 = *(const short8*)&Tr[coff * 72 + 32 + q * 8];
            floatx4 acc = {0.f, 0.f, 0.f, 0.f};
            acc = MFMA(a0, b0, acc);
            acc = MFMA(a1, b1, acc);
            int row0 = w * 16 + q * 4;
            floatx4 badd = *(const floatx4*)&Bcol[coff * 68 + row0];
            floatx4 t = badd + acc;                 // T_new = B + B*T_old
            if (!last) {
                short4v pk = { f2bf(t.x), f2bf(t.y), f2bf(t.z), f2bf(t.w) };
                *(short4v*)&Tw[coff * 72 + row0] = pk;
            } else {
                int col = coff;
                floatx4 cv;
                cv.x = ((row0 + 0) == col ? 1.f : 0.f) + 2.f * t.x;
                cv.y = ((row0 + 1) == col ? 1.f : 0.f) + 2.f * t.y;
                cv.z = ((row0 + 2) == col ? 1.f : 0.f) + 2.f * t.z;
                cv.w = ((row0 + 3) == col ? 1.f : 0.f) + 2.f * t.w;
                if (mode == 0) {
                    outArr[(row0 + 0) * 72 + col] = f2bf(cv.x);
                    outArr[(row0 + 1) * 72 + col] = f2bf(cv.y);
                    outArr[(row0 + 2) * 72 + col] = f2bf(cv.z);
                    outArr[(row0 + 3) * 72 + col] = f2bf(cv.w);
                } else {
                    floatx4 dv = *(const floatx4*)&dg[row0];
                    short4v pk = { f2bf(cv.x * dv.x), f2bf(cv.y * dv.y),
                                   f2bf(cv.z * dv.z), f2bf(cv.w * dv.w) };
                    *(short4v*)&outArr[col * 72 + row0] = pk;
                }
            }
        }
        __syncthreads();
        cur ^= 1;
    }
}

// ---------------------------------------------------------------------------
// k_prep: 2 blocks. Block 0 -> m_left^T (=P), block 1 -> m_right^T (bf16 row-major)
// ---------------------------------------------------------------------------
__global__ __launch_bounds__(256) void k_prep(
        const float* __restrict__ u_l, const float* __restrict__ v_l, const float* __restrict__ dg_l,
        const float* __restrict__ u_r, const float* __restrict__ v_r, const float* __restrict__ dg_r,
        short* __restrict__ wsOut)
{
    __shared__ __align__(16) short Brow[64 * 72];
    __shared__ __align__(16) float Bcol[64 * 68];
    __shared__ __align__(16) short T0[64 * 72];
    __shared__ __align__(16) short T1[64 * 72];
    __shared__ __align__(16) short CvA[64 * 72];
    __shared__ __align__(16) short CuB[64 * 72];

    int tid = threadIdx.x;
    const float* U  = (blockIdx.x == 0) ? u_l  : u_r;
    const float* V  = (blockIdx.x == 0) ? v_l  : v_r;
    const float* DG = (blockIdx.x == 0) ? dg_l : dg_r;
    short* outT = wsOut + blockIdx.x * 4096;

    cayley64(V, DG, CvA, 1, Brow, Bcol, T0, T1, tid);
    __syncthreads();
    cayley64(U, DG, CuB, 0, Brow, Bcol, T0, T1, tid);
    __syncthreads();

    int lane = tid & 63, w = tid >> 6, m = lane & 15, q = lane >> 4;
    int arow = (w * 16 + m) * 72;
    short8 a0 = *(const short8*)&CvA[arow + q * 8];
    short8 a1 = *(const short8*)&CvA[arow + 32 + q * 8];
#pragma unroll
    for (int c = 0; c < 4; ++c) {
        short8 b0 = *(const short8*)&CuB[(c * 16 + m) * 72 + q * 8];
        short8 b1 = *(const short8*)&CuB[(c * 16 + m) * 72 + 32 + q * 8];
        floatx4 acc = {0.f, 0.f, 0.f, 0.f};
        acc = MFMA(a0, b0, acc);
        acc = MFMA(a1, b1, acc);
        int row0 = w * 16 + q * 4, col = c * 16 + m;
        outT[(row0 + 0) * 64 + col] = f2bf(acc.x);
        outT[(row0 + 1) * 64 + col] = f2bf(acc.y);
        outT[(row0 + 2) * 64 + col] = f2bf(acc.z);
        outT[(row0 + 3) * 64 + col] = f2bf(acc.w);
    }
}

// ---------------------------------------------------------------------------
// k_main v5: wave-independent, ZERO barriers.
// Each wave owns WPW whole matrices. Per matrix:
//  - 16 x-float4 loads burst-issued (16 KB/wave in flight), ds from global (L1-hot)
//  - stage1: S = Xs @ Q (tile (r,c)); quads -> per-wave LDS slice as S^T rows
//  - stage2 DUAL: O^T = S^T @ P^T  => A-operand = the S^T frags we just wrote,
//    B-operand = P row-major frags; C/D quad = 4 consecutive out cols of one row
//    -> coalesced float4 stores.
// Only same-wave lgkmcnt waits; no __syncthreads in the loop at all.
// ---------------------------------------------------------------------------
#define WPW 2

__global__ __launch_bounds__(256, 2) void k_main(
        const float* __restrict__ x, const float* __restrict__ dsc,
        const short* __restrict__ mLT, const short* __restrict__ mRT,
        float* __restrict__ out, int N)
{
    // per-wave double-buffered S^T slice: 16 rows x 72 shorts
    __shared__ __align__(16) short STb[4][2][16 * 72];   // 18432 B

    int tid = threadIdx.x, lane = tid & 63, w = tid >> 6;
    int m = lane & 15, q = lane >> 4;
    const int fragoff = q * 8;          // col base of this lane's k-chunk

    // constant fragments: Q B-frags (stage1) and P^T B-frags (stage2, = P row-major)
    short8 qf[4][2], pfB[4][2];
#pragma unroll
    for (int c = 0; c < 4; ++c) {
        qf[c][0] = *(const short8*)&mRT[(c * 16 + m) * 64 + fragoff];
        qf[c][1] = *(const short8*)&mRT[(c * 16 + m) * 64 + 32 + fragoff];
    }
#pragma unroll
    for (int r = 0; r < 4; ++r) {
        pfB[r][0] = *(const short8*)&mLT[(r * 16 + m) * 64 + fragoff];
        pfB[r][1] = *(const short8*)&mLT[(r * 16 + m) * 64 + 32 + fragoff];
    }

    const int wid = blockIdx.x * 4 + w;

#pragma unroll
    for (int i = 0; i < WPW; ++i) {
        int n = wid * WPW + i;
        if (n >= N) break;
        const float* xp = x + (size_t)n * 4096;
        float* op = out + (size_t)n * 4096;

        // ---- burst-issue all 16 x loads (keeps the HBM queue deep)
        floatx4 xf[4][4];
#pragma unroll
        for (int r = 0; r < 4; ++r) {
            const float* rp = xp + (r * 16 + m) * 64 + fragoff;
            xf[r][0] = *(const floatx4*)&rp[0];
            xf[r][1] = *(const floatx4*)&rp[4];
            xf[r][2] = *(const floatx4*)&rp[32];
            xf[r][3] = *(const floatx4*)&rp[36];
        }

        // ---- ds (L1/L2-hot, 16 KB total) + scale + pack
        short8 xa[4][2];
#pragma unroll
        for (int r = 0; r < 4; ++r) {
            const float* dp = dsc + (r * 16 + m) * 64 + fragoff;
            floatx4 d0 = *(const floatx4*)&dp[0];
            floatx4 d1 = *(const floatx4*)&dp[4];
            floatx4 d2 = *(const floatx4*)&dp[32];
            floatx4 d3 = *(const floatx4*)&dp[36];
            xa[r][0] = pack_bf16(xf[r][0] * d0, xf[r][1] * d1);   // k 0..31
            xa[r][1] = pack_bf16(xf[r][2] * d2, xf[r][3] * d3);   // k 32..63
        }

        // ---- per col-tile: stage1 then dual stage2, same wave, no barriers
#pragma unroll
        for (int c = 0; c < 4; ++c) {
            short* stc = &STb[w][c & 1][0];
            // stage1: S tile (r, c); write quad as S^T row (c*16+m), cols r*16+q*4
#pragma unroll
            for (int r = 0; r < 4; ++r) {
                floatx4 s = {0.f, 0.f, 0.f, 0.f};
                s = MFMA(xa[r][0], qf[c][0], s);
                s = MFMA(xa[r][1], qf[c][1], s);
                short4v pk = { f2bf(s.x), f2bf(s.y), f2bf(s.z), f2bf(s.w) };
                *(short4v*)&stc[m * 72 + r * 16 + q * 4] = pk;
            }
            // A-frags of S^T (row c*16+m, k-chunks) — same-wave lgkm wait only
            short8 sb0 = *(const short8*)&stc[m * 72 + fragoff];
            short8 sb1 = *(const short8*)&stc[m * 72 + 32 + fragoff];
            // stage2 dual: O^T = S^T @ P^T; lane quad = out[r*16+m][c*16+q*4 ..+3]
#pragma unroll
            for (int r = 0; r < 4; ++r) {
                floatx4 o = {0.f, 0.f, 0.f, 0.f};
                o = MFMA(sb0, pfB[r][0], o);
                o = MFMA(sb1, pfB[r][1], o);
                *(floatx4*)&op[(r * 16 + m) * 64 + c * 16 + q * 4] = o;
            }
        }
    }
}

extern "C" void kernel_launch(void* const* d_in, const int* in_sizes, int n_in,
                              void* d_out, int out_size, void* d_ws, size_t ws_size,
                              hipStream_t stream) {
    const float* x    = (const float*)d_in[0];
    const float* u_l  = (const float*)d_in[1];
    const float* v_l  = (const float*)d_in[2];
    const float* dg_l = (const float*)d_in[3];
    const float* u_r  = (const float*)d_in[4];
    const float* v_r  = (const float*)d_in[5];
    const float* dg_r = (const float*)d_in[6];
    const float* dsc  = (const float*)d_in[7];
    float* out = (float*)d_out;
    short* ws  = (short*)d_ws;   // [0..4095]=m_left^T bf16, [4096..8191]=m_right^T bf16

    int N = in_sizes[0] / 4096;  // 8192 matrices of 64x64

    hipLaunchKernelGGL(k_prep, dim3(2), dim3(256), 0, stream,
                       u_l, v_l, dg_l, u_r, v_r, dg_r, ws);
    int grid = (N + 4 * WPW - 1) / (4 * WPW);   // one wave per WPW matrices
    hipLaunchKernelGGL(k_main, dim3(grid), dim3(256), 0, stream,
                       x, dsc, ws, ws + 4096, out, N);
}

// Round 5
// 270.147 us; speedup vs baseline: 1.0279x; 1.0279x over previous
//
#include <hip/hip_runtime.h>
#include <hip/hip_bf16.h>

typedef __attribute__((ext_vector_type(8))) short short8;   // 8 bf16 = 4 VGPRs (MFMA A/B frag)
typedef __attribute__((ext_vector_type(4))) short short4v;  // 4 bf16 = 8 B
typedef __attribute__((ext_vector_type(4))) float floatx4;  // MFMA C/D frag

#define MFMA(a, b, c) __builtin_amdgcn_mfma_f32_16x16x32_bf16((a), (b), (c), 0, 0, 0)

// fp32 -> bf16, round-to-nearest-even (bit trick; inputs are finite)
__device__ __forceinline__ short f2bf(float f) {
    unsigned u = __float_as_uint(f);
    u += 0x7fffu + ((u >> 16) & 1u);
    return (short)(u >> 16);
}

__device__ __forceinline__ short8 pack_bf16(floatx4 a, floatx4 b) {
    short8 r;
    r[0] = f2bf(a.x); r[1] = f2bf(a.y); r[2] = f2bf(a.z); r[3] = f2bf(a.w);
    r[4] = f2bf(b.x); r[5] = f2bf(b.y); r[6] = f2bf(b.z); r[7] = f2bf(b.w);
    return r;
}

// ---------------------------------------------------------------------------
// Cayley via Neumann/Horner series on one block (256 threads, 4 waves).
//   B = skew(X)/2 (||B||_2 ~ 0.16);  C = I + 2*(B + B^2 + ...)   NSTEP=6
// mode 0: write C row-major bf16 (B-operand array)
// mode 1: write C^T * diag bf16  (A-operand array, diag folded)
// ---------------------------------------------------------------------------
__device__ void cayley64(const float* __restrict__ X, const float* __restrict__ dg,
                         short* outArr, int mode,
                         short* Brow, float* Bcol, short* T0, short* T1, int tid)
{
    int i0 = (tid * 16) >> 6;
    int j0 = (tid * 16) & 63;
#pragma unroll
    for (int s = 0; s < 16; ++s) {
        int i = i0, j = j0 + s;
        float b = 0.f;
        if (i > j)      b =  0.5f * X[i * 64 + j];
        else if (i < j) b = -0.5f * X[j * 64 + i];
        Brow[i * 72 + j] = f2bf(b);
        Bcol[j * 68 + i] = b;
        T0[j * 72 + i]   = f2bf(b);
    }
    __syncthreads();

    int lane = tid & 63, w = tid >> 6, m = lane & 15, q = lane >> 4;
    int arow = (w * 16 + m) * 72;
    short8 a0 = *(const short8*)&Brow[arow + q * 8];
    short8 a1 = *(const short8*)&Brow[arow + 32 + q * 8];

    short* Tbuf[2] = {T0, T1};
    int cur = 0;
    const int NSTEP = 6;
    for (int step = 0; step < NSTEP; ++step) {
        bool last = (step == NSTEP - 1);
        short* Tr = Tbuf[cur];
        short* Tw = Tbuf[cur ^ 1];
#pragma unroll
        for (int c = 0; c < 4; ++c) {
            int coff = c * 16 + m;
            short8 b0 = *(const short8*)&Tr[coff * 72 + q * 8];
            short8 b1 = *(const short8*)&Tr[coff * 72 + 32 + q * 8];
            floatx4 acc = {0.f, 0.f, 0.f, 0.f};
            acc = MFMA(a0, b0, acc);
            acc = MFMA(a1, b1, acc);
            int row0 = w * 16 + q * 4;
            floatx4 badd = *(const floatx4*)&Bcol[coff * 68 + row0];
            floatx4 t = badd + acc;                 // T_new = B + B*T_old
            if (!last) {
                short4v pk = { f2bf(t.x), f2bf(t.y), f2bf(t.z), f2bf(t.w) };
                *(short4v*)&Tw[coff * 72 + row0] = pk;
            } else {
                int col = coff;
                floatx4 cv;
                cv.x = ((row0 + 0) == col ? 1.f : 0.f) + 2.f * t.x;
                cv.y = ((row0 + 1) == col ? 1.f : 0.f) + 2.f * t.y;
                cv.z = ((row0 + 2) == col ? 1.f : 0.f) + 2.f * t.z;
                cv.w = ((row0 + 3) == col ? 1.f : 0.f) + 2.f * t.w;
                if (mode == 0) {
                    outArr[(row0 + 0) * 72 + col] = f2bf(cv.x);
                    outArr[(row0 + 1) * 72 + col] = f2bf(cv.y);
                    outArr[(row0 + 2) * 72 + col] = f2bf(cv.z);
                    outArr[(row0 + 3) * 72 + col] = f2bf(cv.w);
                } else {
                    floatx4 dv = *(const floatx4*)&dg[row0];
                    short4v pk = { f2bf(cv.x * dv.x), f2bf(cv.y * dv.y),
                                   f2bf(cv.z * dv.z), f2bf(cv.w * dv.w) };
                    *(short4v*)&outArr[col * 72 + row0] = pk;
                }
            }
        }
        __syncthreads();
        cur ^= 1;
    }
}

// ---------------------------------------------------------------------------
// k_prep: 2 blocks. Block 0 -> m_left^T (=P), block 1 -> m_right^T (bf16 row-major)
// ---------------------------------------------------------------------------
__global__ __launch_bounds__(256) void k_prep(
        const float* __restrict__ u_l, const float* __restrict__ v_l, const float* __restrict__ dg_l,
        const float* __restrict__ u_r, const float* __restrict__ v_r, const float* __restrict__ dg_r,
        short* __restrict__ wsOut)
{
    __shared__ __align__(16) short Brow[64 * 72];
    __shared__ __align__(16) float Bcol[64 * 68];
    __shared__ __align__(16) short T0[64 * 72];
    __shared__ __align__(16) short T1[64 * 72];
    __shared__ __align__(16) short CvA[64 * 72];
    __shared__ __align__(16) short CuB[64 * 72];

    int tid = threadIdx.x;
    const float* U  = (blockIdx.x == 0) ? u_l  : u_r;
    const float* V  = (blockIdx.x == 0) ? v_l  : v_r;
    const float* DG = (blockIdx.x == 0) ? dg_l : dg_r;
    short* outT = wsOut + blockIdx.x * 4096;

    cayley64(V, DG, CvA, 1, Brow, Bcol, T0, T1, tid);
    __syncthreads();
    cayley64(U, DG, CuB, 0, Brow, Bcol, T0, T1, tid);
    __syncthreads();

    int lane = tid & 63, w = tid >> 6, m = lane & 15, q = lane >> 4;
    int arow = (w * 16 + m) * 72;
    short8 a0 = *(const short8*)&CvA[arow + q * 8];
    short8 a1 = *(const short8*)&CvA[arow + 32 + q * 8];
#pragma unroll
    for (int c = 0; c < 4; ++c) {
        short8 b0 = *(const short8*)&CuB[(c * 16 + m) * 72 + q * 8];
        short8 b1 = *(const short8*)&CuB[(c * 16 + m) * 72 + 32 + q * 8];
        floatx4 acc = {0.f, 0.f, 0.f, 0.f};
        acc = MFMA(a0, b0, acc);
        acc = MFMA(a1, b1, acc);
        int row0 = w * 16 + q * 4, col = c * 16 + m;
        outT[(row0 + 0) * 64 + col] = f2bf(acc.x);
        outT[(row0 + 1) * 64 + col] = f2bf(acc.y);
        outT[(row0 + 2) * 64 + col] = f2bf(acc.z);
        outT[(row0 + 3) * 64 + col] = f2bf(acc.w);
    }
}

// ---------------------------------------------------------------------------
// k_main v6: ALL global I/O is 1KB-contiguous per instruction (fill-kernel
// pattern); all lane rearrangement via LDS. Wave-independent, zero in-loop
// barriers. Per wave, per matrix:
//   1. 16x contiguous float4 loads (lane l <- elem j*256 + l*4)
//   2. scale by LDS-resident dscale, pack bf16 -> per-wave Xa (A-frag layout)
//   3. stage1: S = Xs@Q per col-tile; S^T quads -> per-wave ST; sb-frags of
//      ALL 4 col-tiles kept in registers
//   4. stage2 per row-quarter r: 4 MFMAs (dual form O^T = S^T @ P^T) -> f32
//      quads into per-wave Oq -> contiguous readback -> 1KB contiguous stores
// ---------------------------------------------------------------------------
#define WPW 2

__global__ __launch_bounds__(256, 2) void k_main(
        const float* __restrict__ x, const float* __restrict__ dsc,
        const short* __restrict__ mLT, const short* __restrict__ mRT,
        float* __restrict__ out, int N)
{
    __shared__ __align__(16) float DS[4096];          // 16 KB dscale (block-shared)
    __shared__ __align__(16) short Xa[4][64 * 72];    // 36 KB: per-wave A-frag staging
    __shared__ __align__(16) short ST[4][16 * 72];    //  9 KB: per-wave S^T slice
    __shared__ __align__(16) float Oq[4][16 * 68];    // 17 KB: per-wave O row-quarter

    int tid = threadIdx.x, lane = tid & 63, w = tid >> 6;
    int m = lane & 15, q = lane >> 4;
    const int fragoff = q * 8;

    // ---- prologue: stage dscale into LDS (contiguous), once
#pragma unroll
    for (int j = 0; j < 4; ++j) {
        int e = (j * 256 + tid) * 4;
        *(floatx4*)&DS[e] = *(const floatx4*)&dsc[e];
    }

    // constant fragments: Q^T rows (stage1 B-operand), P rows (stage2 B-operand)
    short8 qf[4][2], pfB[4][2];
#pragma unroll
    for (int c = 0; c < 4; ++c) {
        qf[c][0] = *(const short8*)&mRT[(c * 16 + m) * 64 + fragoff];
        qf[c][1] = *(const short8*)&mRT[(c * 16 + m) * 64 + 32 + fragoff];
    }
#pragma unroll
    for (int r = 0; r < 4; ++r) {
        pfB[r][0] = *(const short8*)&mLT[(r * 16 + m) * 64 + fragoff];
        pfB[r][1] = *(const short8*)&mLT[(r * 16 + m) * 64 + 32 + fragoff];
    }
    __syncthreads();   // DS visible to all waves (only barrier in the kernel)

    short* xa_lds = &Xa[w][0];
    short* st_lds = &ST[w][0];
    float* oq_lds = &Oq[w][0];

    const int wid = blockIdx.x * 4 + w;
    const int n0 = wid * WPW;

    // ---- prefetch matrix 0 (contiguous: lane l gets float4 at j*256 + l*4)
    floatx4 xv[16];
    if (n0 < N) {
        const float* xp = x + (size_t)n0 * 4096 + lane * 4;
#pragma unroll
        for (int j = 0; j < 16; ++j) xv[j] = *(const floatx4*)&xp[j * 256];
    }

#pragma unroll
    for (int it = 0; it < WPW; ++it) {
        int n = n0 + it;
        if (n >= N) break;

        // ---- scale + pack bf16 -> Xa (row-major stride 72, A-frag friendly)
        // element j*256 + lane*4 -> row = (lane>>4) + j*4, col = (lane&15)*4
#pragma unroll
        for (int j = 0; j < 16; ++j) {
            floatx4 dv = *(const floatx4*)&DS[j * 256 + lane * 4];
            floatx4 v = xv[j] * dv;
            short4v pk = { f2bf(v.x), f2bf(v.y), f2bf(v.z), f2bf(v.w) };
            *(short4v*)&xa_lds[((lane >> 4) + j * 4) * 72 + (lane & 15) * 4] = pk;
        }

        // ---- issue next matrix's loads now (xv regs free; overlaps MFMA phase)
        floatx4 nxv[16];
        bool pfn = (it + 1 < WPW) && (n + 1 < N);
        if (pfn) {
            const float* xp = x + (size_t)(n + 1) * 4096 + lane * 4;
#pragma unroll
            for (int j = 0; j < 16; ++j) nxv[j] = *(const floatx4*)&xp[j * 256];
        }

        // ---- A-frags from LDS (same-wave, in-order: writes above complete first)
        short8 xaf[4][2];
#pragma unroll
        for (int r = 0; r < 4; ++r) {
            xaf[r][0] = *(const short8*)&xa_lds[(r * 16 + m) * 72 + fragoff];
            xaf[r][1] = *(const short8*)&xa_lds[(r * 16 + m) * 72 + 32 + fragoff];
        }

        // ---- stage1: per col-tile c: S tile -> S^T quads -> LDS -> sb frags (regs)
        short8 sb[4][2];
#pragma unroll
        for (int c = 0; c < 4; ++c) {
#pragma unroll
            for (int r = 0; r < 4; ++r) {
                floatx4 s = {0.f, 0.f, 0.f, 0.f};
                s = MFMA(xaf[r][0], qf[c][0], s);
                s = MFMA(xaf[r][1], qf[c][1], s);
                short4v pk = { f2bf(s.x), f2bf(s.y), f2bf(s.z), f2bf(s.w) };
                *(short4v*)&st_lds[m * 72 + r * 16 + q * 4] = pk;
            }
            sb[c][0] = *(const short8*)&st_lds[m * 72 + fragoff];
            sb[c][1] = *(const short8*)&st_lds[m * 72 + 32 + fragoff];
        }

        // ---- stage2 per row-quarter: O^T = S^T @ P^T; quads -> Oq -> contig store
        float* op = out + (size_t)n * 4096;
#pragma unroll
        for (int r = 0; r < 4; ++r) {
#pragma unroll
            for (int c = 0; c < 4; ++c) {
                floatx4 o = {0.f, 0.f, 0.f, 0.f};
                o = MFMA(sb[c][0], pfB[r][0], o);
                o = MFMA(sb[c][1], pfB[r][1], o);
                // quad = out[r*16+m][c*16+q*4 .. +3]
                *(floatx4*)&oq_lds[m * 68 + c * 16 + q * 4] = o;
            }
            // readback contiguous + 1KB-contiguous global stores
#pragma unroll
            for (int j = 0; j < 4; ++j) {
                int row = (lane >> 4) + j * 4, col = (lane & 15) * 4;
                floatx4 v = *(const floatx4*)&oq_lds[row * 68 + col];
                *(floatx4*)&op[r * 1024 + j * 256 + lane * 4] = v;
            }
        }

        if (pfn) {
#pragma unroll
            for (int j = 0; j < 16; ++j) xv[j] = nxv[j];
        }
    }
}

extern "C" void kernel_launch(void* const* d_in, const int* in_sizes, int n_in,
                              void* d_out, int out_size, void* d_ws, size_t ws_size,
                              hipStream_t stream) {
    const float* x    = (const float*)d_in[0];
    const float* u_l  = (const float*)d_in[1];
    const float* v_l  = (const float*)d_in[2];
    const float* dg_l = (const float*)d_in[3];
    const float* u_r  = (const float*)d_in[4];
    const float* v_r  = (const float*)d_in[5];
    const float* dg_r = (const float*)d_in[6];
    const float* dsc  = (const float*)d_in[7];
    float* out = (float*)d_out;
    short* ws  = (short*)d_ws;   // [0..4095]=m_left^T bf16, [4096..8191]=m_right^T bf16

    int N = in_sizes[0] / 4096;  // 8192 matrices of 64x64

    hipLaunchKernelGGL(k_prep, dim3(2), dim3(256), 0, stream,
                       u_l, v_l, dg_l, u_r, v_r, dg_r, ws);
    int grid = (N + 4 * WPW - 1) / (4 * WPW);
    hipLaunchKernelGGL(k_main, dim3(grid), dim3(256), 0, stream,
                       x, dsc, ws, ws + 4096, out, N);
}